// Round 4
// baseline (8598.392 us; speedup 1.0000x reference)
//
#include <hip/hip_runtime.h>
#include <hip/hip_bf16.h>

#define Hd 768
#define Bd 32
#define Td 1024
#define Md (Bd*Td)

// scan: 16 independent groups (1 batch-pair each) x 16 WGs (48 g-rows each)
#define NPAIR 16
#define SPW   16        // slices (WGs) per group
#define GPW   48        // g-rows per WG
#define RINGD 4         // ring depth (correctness requires >= 4, see protocol)
#define SENT_U 0x7FC00000u   // qNaN sentinel; tanh output bits can never equal it
#define RVALS (2*Hd)    // floats per ring region per group (2 batches x 768)

typedef unsigned int u32x4 __attribute__((ext_vector_type(4)));
typedef unsigned int u32x2 __attribute__((ext_vector_type(2)));

// ---------------- init: ring region 0 = h0, regions 1..3 = sentinel ----------------
__global__ __launch_bounds__(256) void k_init(const float* __restrict__ hid,
                                              unsigned* __restrict__ ring) {
    int i = blockIdx.x * 256 + threadIdx.x;          // 16*4*1536 = 98304 total
    const int p   = i / (RINGD * RVALS);
    const int rem = i % (RINGD * RVALS);
    const int r   = rem / RVALS;
    const int q   = rem % RVALS;
    const int bb  = q / Hd;
    const int k   = q % Hd;
    unsigned v = SENT_U;
    if (r == 0) v = ((const unsigned*)hid)[(p * 2 + bb) * Hd + k];
    ring[i] = v;
}

// ---------------- phase 1: gi_r / gi_n GEMM (unchanged) ----------------
__global__ __launch_bounds__(256, 2) void k_gemm(const float* __restrict__ A,
                                                 const float* __restrict__ Wih,
                                                 const float* __restrict__ bih,
                                                 float* __restrict__ giR,
                                                 float* __restrict__ giN) {
    __shared__ float As[16][68];
    __shared__ float Brs[16][68];
    __shared__ float Bns[16][68];
    const int tid = threadIdx.x;
    const int mb = blockIdx.x & 511;
    const int nb = blockIdx.x >> 9;
    const int lm = tid >> 2;
    const int lk = (tid & 3) << 2;
    const int tx = tid & 15;
    const int ty = tid >> 4;

    const float* pA = A   + (size_t)(mb * 64 + lm) * Hd + lk;
    const float* pR = Wih + (size_t)(nb * 64 + lm) * Hd + lk;
    const float* pN = Wih + (size_t)(2 * Hd + nb * 64 + lm) * Hd + lk;

    float accR[4][4] = {{0.f}};
    float accN[4][4] = {{0.f}};

    for (int kt = 0; kt < Hd; kt += 16) {
        float4 va = *(const float4*)(pA + kt);
        float4 vr = *(const float4*)(pR + kt);
        float4 vn = *(const float4*)(pN + kt);
        __syncthreads();
        As[lk+0][lm]=va.x; As[lk+1][lm]=va.y; As[lk+2][lm]=va.z; As[lk+3][lm]=va.w;
        Brs[lk+0][lm]=vr.x; Brs[lk+1][lm]=vr.y; Brs[lk+2][lm]=vr.z; Brs[lk+3][lm]=vr.w;
        Bns[lk+0][lm]=vn.x; Bns[lk+1][lm]=vn.y; Bns[lk+2][lm]=vn.z; Bns[lk+3][lm]=vn.w;
        __syncthreads();
        #pragma unroll
        for (int k = 0; k < 16; ++k) {
            float4 a4 = *(const float4*)&As[k][ty << 2];
            float4 r4 = *(const float4*)&Brs[k][tx << 2];
            float4 n4 = *(const float4*)&Bns[k][tx << 2];
            float av[4] = {a4.x, a4.y, a4.z, a4.w};
            float rv[4] = {r4.x, r4.y, r4.z, r4.w};
            float nv[4] = {n4.x, n4.y, n4.z, n4.w};
            #pragma unroll
            for (int i = 0; i < 4; ++i)
                #pragma unroll
                for (int j = 0; j < 4; ++j) {
                    accR[i][j] += av[i] * rv[j];
                    accN[i][j] += av[i] * nv[j];
                }
        }
    }

    const int m0 = mb * 64 + (ty << 2);
    const int g0 = nb * 64 + (tx << 2);
    float4 bR = *(const float4*)(bih + g0);
    float4 bN = *(const float4*)(bih + 2 * Hd + g0);
    #pragma unroll
    for (int i = 0; i < 4; ++i) {
        float4 oR = { accR[i][0]+bR.x, accR[i][1]+bR.y, accR[i][2]+bR.z, accR[i][3]+bR.w };
        float4 oN = { accN[i][0]+bN.x, accN[i][1]+bN.y, accN[i][2]+bN.z, accN[i][3]+bN.w };
        *(float4*)(giR + (size_t)(m0 + i) * Hd + g0) = oR;
        *(float4*)(giN + (size_t)(m0 + i) * Hd + g0) = oN;
    }
}

// ---------------- phase 2: sentinel-ring persistent scan ----------------
// Same protocol as R3 (reset t+2 / poll t / vmcnt / produce t+1), but the
// coherent traffic is batched: the poll is ONE dwordx4 + ONE dwordx2 (sc0 sc1)
// with a single vmcnt(0) per round, and produce/reset stores are raw
// back-to-back sc0sc1 stores (no compiler-inserted per-op waits).
__global__ __launch_bounds__(256, 1) void k_scan(const float* __restrict__ Whh,
                                                 const float* __restrict__ bhh,
                                                 const float* __restrict__ giR,
                                                 float* __restrict__ out,   // giN in, h out
                                                 unsigned* __restrict__ ring) {
    __shared__ float hs[2][2][Hd];     // parity x batch x k
    const int tid = threadIdx.x;
    const int gl  = tid >> 4;          // 0..15
    const int ks  = tid & 15;          // 0..15
    const int p   = blockIdx.x >> 4;   // pair 0..15
    const int s   = blockIdx.x & 15;   // slice 0..15
    const int b0  = p * 2;
    unsigned* ringp = ring + (size_t)p * RINGD * RVALS;

    // stationary weights: wr/wn[sub][j*4+c] <-> row g=48s+16*sub+gl, k=ks*4+64j+c
    float wr[3][48], wn[3][48];
    int gbase[3];
    #pragma unroll
    for (int sub = 0; sub < 3; ++sub) {
        const int g = s * GPW + sub * 16 + gl;
        gbase[sub] = g;
        #pragma unroll
        for (int j = 0; j < 12; ++j) {
            float4 a = *(const float4*)(Whh + (size_t)g * Hd + (ks << 2) + (j << 6));
            float4 b = *(const float4*)(Whh + (size_t)(2 * Hd + g) * Hd + (ks << 2) + (j << 6));
            wr[sub][j*4+0]=a.x; wr[sub][j*4+1]=a.y; wr[sub][j*4+2]=a.z; wr[sub][j*4+3]=a.w;
            wn[sub][j*4+0]=b.x; wn[sub][j*4+1]=b.y; wn[sub][j*4+2]=b.z; wn[sub][j*4+3]=b.w;
        }
    }
    float br[3], bn[3];
    #pragma unroll
    for (int sub = 0; sub < 3; ++sub) {
        br[sub] = bhh[gbase[sub]];
        bn[sub] = bhh[2 * Hd + gbase[sub]];
    }

    // gi for t=0 (ks==0 lanes use them)
    float gR[3][2], gN[3][2];
    if (ks == 0) {
        #pragma unroll
        for (int sub = 0; sub < 3; ++sub)
            #pragma unroll
            for (int bb = 0; bb < 2; ++bb) {
                const size_t mi = ((size_t)(b0 + bb) * Td) * Hd + gbase[sub];
                gR[sub][bb] = giR[mi];
                gN[sub][bb] = out[mi];
            }
    }

    for (int t = 0; t < Td; ++t) {
        // 1. reset own slice of region (t+2)%4 (acks overlap poll+compute)
        if (tid < 2 * GPW) {
            const int bb = tid / GPW, kk = tid - (tid / GPW) * GPW;
            const unsigned* rp = ringp + ((t + 2) & 3) * RVALS + bb * Hd + s * GPW + kk;
            unsigned sv = SENT_U;
            asm volatile("global_store_dword %0, %1, off sc0 sc1"
                         :: "v"(rp), "v"(sv) : "memory");
        }

        // 2. prefetch gi[t+1] early: HBM latency hides under the poll wait
        float gR2[3][2], gN2[3][2];
        if (ks == 0 && t + 1 < Td) {
            #pragma unroll
            for (int sub = 0; sub < 3; ++sub)
                #pragma unroll
                for (int bb = 0; bb < 2; ++bb) {
                    const size_t mi = ((size_t)(b0 + bb) * Td + (t + 1)) * Hd + gbase[sub];
                    gR2[sub][bb] = giR[mi];
                    gN2[sub][bb] = out[mi];
                }
        }

        // 3. poll-load h_t: 6 words/thread in TWO loads + ONE vmcnt per round
        const unsigned* src = ringp + (t & 3) * RVALS;
        const unsigned* a0 = src + (tid << 2);          // words [4*tid, 4*tid+4)
        const unsigned* a1 = src + 1024 + (tid << 1);   // words [1024+2*tid, ..+2)
        u32x4 w4; u32x2 w2;
        for (;;) {
            asm volatile(
                "global_load_dwordx4 %0, %2, off sc0 sc1\n\t"
                "global_load_dwordx2 %1, %3, off sc0 sc1\n\t"
                "s_waitcnt vmcnt(0)"
                : "=&v"(w4), "=&v"(w2)
                : "v"(a0), "v"(a1)
                : "memory");
            const int bad = (w4.x == SENT_U) | (w4.y == SENT_U) | (w4.z == SENT_U) |
                            (w4.w == SENT_U) | (w2.x == SENT_U) | (w2.y == SENT_U);
            if (!__any(bad)) break;
            __builtin_amdgcn_s_sleep(1);
        }
        {
            unsigned* hsl = (unsigned*)&hs[t & 1][0][0];
            *(u32x4*)(hsl + (tid << 2)) = w4;
            *(u32x2*)(hsl + 1024 + (tid << 1)) = w2;
        }
        __syncthreads();

        // 4. matvec: 3 subtiles x 2 batches x 48 k x 2 gates
        float aR[3][2], aN[3][2];
        #pragma unroll
        for (int sub = 0; sub < 3; ++sub)
            #pragma unroll
            for (int bb = 0; bb < 2; ++bb) { aR[sub][bb] = 0.f; aN[sub][bb] = 0.f; }
        #pragma unroll
        for (int bb = 0; bb < 2; ++bb) {
            #pragma unroll
            for (int j = 0; j < 12; ++j) {
                float4 h4 = *(const float4*)&hs[t & 1][bb][(ks << 2) + (j << 6)];
                #pragma unroll
                for (int sub = 0; sub < 3; ++sub) {
                    aR[sub][bb] = fmaf(h4.x, wr[sub][j*4+0], aR[sub][bb]);
                    aN[sub][bb] = fmaf(h4.x, wn[sub][j*4+0], aN[sub][bb]);
                    aR[sub][bb] = fmaf(h4.y, wr[sub][j*4+1], aR[sub][bb]);
                    aN[sub][bb] = fmaf(h4.y, wn[sub][j*4+1], aN[sub][bb]);
                    aR[sub][bb] = fmaf(h4.z, wr[sub][j*4+2], aR[sub][bb]);
                    aN[sub][bb] = fmaf(h4.z, wn[sub][j*4+2], aN[sub][bb]);
                    aR[sub][bb] = fmaf(h4.w, wr[sub][j*4+3], aR[sub][bb]);
                    aN[sub][bb] = fmaf(h4.w, wn[sub][j*4+3], aN[sub][bb]);
                }
            }
        }
        #pragma unroll
        for (int sub = 0; sub < 3; ++sub)
            #pragma unroll
            for (int bb = 0; bb < 2; ++bb)
                #pragma unroll
                for (int off = 8; off >= 1; off >>= 1) {
                    aR[sub][bb] += __shfl_xor(aR[sub][bb], off);
                    aN[sub][bb] += __shfl_xor(aN[sub][bb], off);
                }

        // order reset acks (and all prior vmem) before the produce stores
        asm volatile("s_waitcnt vmcnt(0)" ::: "memory");

        // 5. produce h_{t+1} into region (t+1)%4, then out[:,t]
        if (ks == 0) {
            unsigned* dst = ringp + ((t + 1) & 3) * RVALS;
            float hn[3][2];
            #pragma unroll
            for (int sub = 0; sub < 3; ++sub)
                #pragma unroll
                for (int bb = 0; bb < 2; ++bb) {
                    const float r = 1.f / (1.f + __expf(-(gR[sub][bb] + aR[sub][bb] + br[sub])));
                    const float h = tanhf(gN[sub][bb] + r * (aN[sub][bb] + bn[sub]));
                    hn[sub][bb] = h;
                    const unsigned* dp = dst + bb * Hd + gbase[sub];
                    const unsigned hbits = __float_as_uint(h);
                    asm volatile("global_store_dword %0, %1, off sc0 sc1"
                                 :: "v"(dp), "v"(hbits) : "memory");
                }
            #pragma unroll
            for (int sub = 0; sub < 3; ++sub)
                #pragma unroll
                for (int bb = 0; bb < 2; ++bb)
                    out[((size_t)(b0 + bb) * Td + t) * Hd + gbase[sub]] = hn[sub][bb];
            #pragma unroll
            for (int sub = 0; sub < 3; ++sub)
                #pragma unroll
                for (int bb = 0; bb < 2; ++bb) { gR[sub][bb] = gR2[sub][bb]; gN[sub][bb] = gN2[sub][bb]; }
        }
        __syncthreads();   // parity-buffer safety: no wave may run 2 steps ahead
    }
}

extern "C" void kernel_launch(void* const* d_in, const int* in_sizes, int n_in,
                              void* d_out, int out_size, void* d_ws, size_t ws_size,
                              hipStream_t stream) {
    const float* input  = (const float*)d_in[0];
    const float* hidden = (const float*)d_in[1];
    const float* Wih    = (const float*)d_in[2];
    const float* Whh    = (const float*)d_in[3];
    const float* bih    = (const float*)d_in[4];
    const float* bhh    = (const float*)d_in[5];
    float* out = (float*)d_out;

    // ws layout: gi_r (M*H f32) | sentinel ring (16 pairs x 4 x 1536 u32)
    float*    giR  = (float*)d_ws;
    unsigned* ring = (unsigned*)(giR + (size_t)Md * Hd);

    k_init<<<(NPAIR * RINGD * RVALS) / 256, 256, 0, stream>>>(hidden, ring);
    k_gemm<<<512 * 12, 256, 0, stream>>>(input, Wih, bih, giR, out);
    k_scan<<<NPAIR * SPW, 256, 0, stream>>>(Whh, bhh, giR, out, ring);
}

// Round 6
// 5998.839 us; speedup vs baseline: 1.4333x; 1.4333x over previous
//
#include <hip/hip_runtime.h>
#include <hip/hip_bf16.h>

#define Hd 768
#define Bd 32
#define Td 1024
#define Md (Bd*Td)

// scan: 16 independent groups (1 batch-pair each) x 16 WGs (48 g-rows each)
#define NPAIR 16
#define SPW   16        // slices (WGs) per group
#define GPW   48        // g-rows per WG
#define THRS  384       // threads per scan WG (6 waves)
#define RINGD 4         // ring depth (protocol-proven in R3)
#define SENT_U 0x7FC00000u   // qNaN sentinel; tanh output bits can never equal it
#define RVALS (2*Hd)    // words per ring region per group (2 batches x 768)

typedef unsigned int u32x4 __attribute__((ext_vector_type(4)));

// ---------------- init: ring region 0 = h0, regions 1..3 = sentinel ----------------
__global__ __launch_bounds__(256) void k_init(const float* __restrict__ hid,
                                              unsigned* __restrict__ ring) {
    int i = blockIdx.x * 256 + threadIdx.x;          // 16*4*1536 = 98304 total
    const int p   = i / (RINGD * RVALS);
    const int rem = i % (RINGD * RVALS);
    const int r   = rem / RVALS;
    const int q   = rem % RVALS;
    const int bb  = q / Hd;
    const int k   = q % Hd;
    unsigned v = SENT_U;
    if (r == 0) v = ((const unsigned*)hid)[(p * 2 + bb) * Hd + k];
    ring[i] = v;
}

// ---------------- phase 1: gi_r / gi_n GEMM (unchanged) ----------------
__global__ __launch_bounds__(256, 2) void k_gemm(const float* __restrict__ A,
                                                 const float* __restrict__ Wih,
                                                 const float* __restrict__ bih,
                                                 float* __restrict__ giR,
                                                 float* __restrict__ giN) {
    __shared__ float As[16][68];
    __shared__ float Brs[16][68];
    __shared__ float Bns[16][68];
    const int tid = threadIdx.x;
    const int mb = blockIdx.x & 511;
    const int nb = blockIdx.x >> 9;
    const int lm = tid >> 2;
    const int lk = (tid & 3) << 2;
    const int tx = tid & 15;
    const int ty = tid >> 4;

    const float* pA = A   + (size_t)(mb * 64 + lm) * Hd + lk;
    const float* pR = Wih + (size_t)(nb * 64 + lm) * Hd + lk;
    const float* pN = Wih + (size_t)(2 * Hd + nb * 64 + lm) * Hd + lk;

    float accR[4][4] = {{0.f}};
    float accN[4][4] = {{0.f}};

    for (int kt = 0; kt < Hd; kt += 16) {
        float4 va = *(const float4*)(pA + kt);
        float4 vr = *(const float4*)(pR + kt);
        float4 vn = *(const float4*)(pN + kt);
        __syncthreads();
        As[lk+0][lm]=va.x; As[lk+1][lm]=va.y; As[lk+2][lm]=va.z; As[lk+3][lm]=va.w;
        Brs[lk+0][lm]=vr.x; Brs[lk+1][lm]=vr.y; Brs[lk+2][lm]=vr.z; Brs[lk+3][lm]=vr.w;
        Bns[lk+0][lm]=vn.x; Bns[lk+1][lm]=vn.y; Bns[lk+2][lm]=vn.z; Bns[lk+3][lm]=vn.w;
        __syncthreads();
        #pragma unroll
        for (int k = 0; k < 16; ++k) {
            float4 a4 = *(const float4*)&As[k][ty << 2];
            float4 r4 = *(const float4*)&Brs[k][tx << 2];
            float4 n4 = *(const float4*)&Bns[k][tx << 2];
            float av[4] = {a4.x, a4.y, a4.z, a4.w};
            float rv[4] = {r4.x, r4.y, r4.z, r4.w};
            float nv[4] = {n4.x, n4.y, n4.z, n4.w};
            #pragma unroll
            for (int i = 0; i < 4; ++i)
                #pragma unroll
                for (int j = 0; j < 4; ++j) {
                    accR[i][j] += av[i] * rv[j];
                    accN[i][j] += av[i] * nv[j];
                }
        }
    }

    const int m0 = mb * 64 + (ty << 2);
    const int g0 = nb * 64 + (tx << 2);
    float4 bR = *(const float4*)(bih + g0);
    float4 bN = *(const float4*)(bih + 2 * Hd + g0);
    #pragma unroll
    for (int i = 0; i < 4; ++i) {
        float4 oR = { accR[i][0]+bR.x, accR[i][1]+bR.y, accR[i][2]+bR.z, accR[i][3]+bR.w };
        float4 oN = { accN[i][0]+bN.x, accN[i][1]+bN.y, accN[i][2]+bN.z, accN[i][3]+bN.w };
        *(float4*)(giR + (size_t)(m0 + i) * Hd + g0) = oR;
        *(float4*)(giN + (size_t)(m0 + i) * Hd + g0) = oN;
    }
}

// ---------------- phase 2: sentinel-ring scan, incremental poll, no spills ----
// 256 WGs = 16 pairs x 16 slices; 384 threads = (gl 0..23) x (ks 0..15).
// WG owns 48 g-rows as 2 subtiles of 24; weights 192 f32/thread (fits VGPR).
// Poll: each thread owns ONE dwordx4 of the region; once non-sentinel it
// stages to LDS and stops loading. Consensus via __syncthreads_or.
// Protocol (proven R3): poll t -> reset (t+2) -> compute -> vmcnt(0) ->
// produce (t+1). vmcnt-before-produce orders reset acks ahead of new data.
__global__ __launch_bounds__(THRS, 2) void k_scan(const float* __restrict__ Whh,
                                                  const float* __restrict__ bhh,
                                                  const float* __restrict__ giR,
                                                  float* __restrict__ out,   // giN in, h out
                                                  unsigned* __restrict__ ring) {
    __shared__ float hs[2][RVALS];   // parity x (bb*768 + k)
    __shared__ float po[2 * GPW];    // produce staging: bb*48 + (g - s*48)
    const int tid = threadIdx.x;
    const int gl  = tid >> 4;          // 0..23
    const int ks  = tid & 15;          // 0..15
    const int p   = blockIdx.x >> 4;   // pair 0..15
    const int s   = blockIdx.x & 15;   // slice 0..15
    const int b0  = p * 2;
    unsigned* ringp = ring + (size_t)p * RINGD * RVALS;

    // stationary weights: wr/wn[sub][j*4+c] <-> row g=48s+24*sub+gl, k=ks*4+64j+c
    float wr[2][48], wn[2][48];
    int gbase[2];
    #pragma unroll
    for (int sub = 0; sub < 2; ++sub) {
        const int g = s * GPW + sub * 24 + gl;
        gbase[sub] = g;
        #pragma unroll
        for (int j = 0; j < 12; ++j) {
            float4 a = *(const float4*)(Whh + (size_t)g * Hd + (ks << 2) + (j << 6));
            float4 b = *(const float4*)(Whh + (size_t)(2 * Hd + g) * Hd + (ks << 2) + (j << 6));
            wr[sub][j*4+0]=a.x; wr[sub][j*4+1]=a.y; wr[sub][j*4+2]=a.z; wr[sub][j*4+3]=a.w;
            wn[sub][j*4+0]=b.x; wn[sub][j*4+1]=b.y; wn[sub][j*4+2]=b.z; wn[sub][j*4+3]=b.w;
        }
    }
    float br[2], bn[2];
    #pragma unroll
    for (int sub = 0; sub < 2; ++sub) {
        br[sub] = bhh[gbase[sub]];
        bn[sub] = bhh[2 * Hd + gbase[sub]];
    }

    // gi for t=0 (ks==0 lanes)
    float gR[2][2], gN[2][2];
    if (ks == 0) {
        #pragma unroll
        for (int sub = 0; sub < 2; ++sub)
            #pragma unroll
            for (int bb = 0; bb < 2; ++bb) {
                const size_t mi = ((size_t)(b0 + bb) * Td) * Hd + gbase[sub];
                gR[sub][bb] = giR[mi];
                gN[sub][bb] = out[mi];
            }
    }

    for (int t = 0; t < Td; ++t) {
        // ---- incremental poll of region t%4: one dwordx4 per thread ----
        const unsigned* myp = ringp + (t & 3) * RVALS + (tid << 2);
        unsigned* hsl = (unsigned*)hs[t & 1];
        int need = 1;
        for (;;) {
            if (need) {
                u32x4 w;
                asm volatile(
                    "global_load_dwordx4 %0, %1, off sc0 sc1\n\t"
                    "s_waitcnt vmcnt(0)"
                    : "=v"(w) : "v"(myp) : "memory");
                if (w.x != SENT_U && w.y != SENT_U && w.z != SENT_U && w.w != SENT_U) {
                    *(u32x4*)(hsl + (tid << 2)) = w;
                    need = 0;
                }
            }
            if (!__syncthreads_or(need)) break;
            if (need) __builtin_amdgcn_s_sleep(1);
        }

        // ---- reset own slice of region (t+2)%4 (acks overlap compute) ----
        if (tid < 24) {
            const int bb = tid / 12, q = tid % 12;
            const unsigned* rp = ringp + ((t + 2) & 3) * RVALS + bb * Hd + s * GPW + (q << 2);
            u32x4 sv = { SENT_U, SENT_U, SENT_U, SENT_U };
            asm volatile("global_store_dwordx4 %0, %1, off sc0 sc1"
                         :: "v"(rp), "v"(sv) : "memory");
        }

        // ---- gi prefetch t+1 (plain cached loads; complete during compute) ----
        float gR2[2][2], gN2[2][2];
        if (ks == 0 && t + 1 < Td) {
            #pragma unroll
            for (int sub = 0; sub < 2; ++sub)
                #pragma unroll
                for (int bb = 0; bb < 2; ++bb) {
                    const size_t mi = ((size_t)(b0 + bb) * Td + (t + 1)) * Hd + gbase[sub];
                    gR2[sub][bb] = giR[mi];
                    gN2[sub][bb] = out[mi];
                }
        }

        // ---- matvec: 2 subtiles x 2 batches x 48 k x 2 gates = 384 FMA ----
        float aR[2][2], aN[2][2];
        #pragma unroll
        for (int sub = 0; sub < 2; ++sub)
            #pragma unroll
            for (int bb = 0; bb < 2; ++bb) { aR[sub][bb] = 0.f; aN[sub][bb] = 0.f; }
        #pragma unroll
        for (int bb = 0; bb < 2; ++bb) {
            #pragma unroll
            for (int j = 0; j < 12; ++j) {
                float4 h4 = *(const float4*)&hs[t & 1][bb * Hd + (ks << 2) + (j << 6)];
                #pragma unroll
                for (int sub = 0; sub < 2; ++sub) {
                    aR[sub][bb] = fmaf(h4.x, wr[sub][j*4+0], aR[sub][bb]);
                    aN[sub][bb] = fmaf(h4.x, wn[sub][j*4+0], aN[sub][bb]);
                    aR[sub][bb] = fmaf(h4.y, wr[sub][j*4+1], aR[sub][bb]);
                    aN[sub][bb] = fmaf(h4.y, wn[sub][j*4+1], aN[sub][bb]);
                    aR[sub][bb] = fmaf(h4.z, wr[sub][j*4+2], aR[sub][bb]);
                    aN[sub][bb] = fmaf(h4.z, wn[sub][j*4+2], aN[sub][bb]);
                    aR[sub][bb] = fmaf(h4.w, wr[sub][j*4+3], aR[sub][bb]);
                    aN[sub][bb] = fmaf(h4.w, wn[sub][j*4+3], aN[sub][bb]);
                }
            }
        }
        #pragma unroll
        for (int sub = 0; sub < 2; ++sub)
            #pragma unroll
            for (int bb = 0; bb < 2; ++bb)
                #pragma unroll
                for (int off = 8; off >= 1; off >>= 1) {
                    aR[sub][bb] += __shfl_xor(aR[sub][bb], off);
                    aN[sub][bb] += __shfl_xor(aN[sub][bb], off);
                }

        // ---- epilogue: gates on ks==0 lanes, stage into po ----
        if (ks == 0) {
            #pragma unroll
            for (int sub = 0; sub < 2; ++sub)
                #pragma unroll
                for (int bb = 0; bb < 2; ++bb) {
                    const float r = 1.f / (1.f + __expf(-(gR[sub][bb] + aR[sub][bb] + br[sub])));
                    const float h = tanhf(gN[sub][bb] + r * (aN[sub][bb] + bn[sub]));
                    po[bb * GPW + sub * 24 + gl] = h;
                }
            if (t + 1 < Td) {
                #pragma unroll
                for (int sub = 0; sub < 2; ++sub)
                    #pragma unroll
                    for (int bb = 0; bb < 2; ++bb) { gR[sub][bb] = gR2[sub][bb]; gN[sub][bb] = gN2[sub][bb]; }
            }
        }

        // order reset acks (and all prior vmem) before the produce stores
        asm volatile("s_waitcnt vmcnt(0)" ::: "memory");
        __syncthreads();

        // ---- produce h_{t+1} slice + out[:,t] as dwordx4 (24 threads) ----
        if (tid < 24) {
            const int bb = tid / 12, q = tid % 12;
            // u32x4 (ext_vector) is asm-operand-legal; HIP float4 struct is not
            u32x4 hv = *(const u32x4*)((const unsigned*)po + (tid << 2));
            const unsigned* dp = ringp + ((t + 1) & 3) * RVALS + bb * Hd + s * GPW + (q << 2);
            asm volatile("global_store_dwordx4 %0, %1, off sc0 sc1"
                         :: "v"(dp), "v"(hv) : "memory");
            *(u32x4*)(out + ((size_t)(b0 + bb) * Td + t) * Hd + s * GPW + (q << 2)) = hv;
        }
        __syncthreads();   // parity/staging safety
    }
}

extern "C" void kernel_launch(void* const* d_in, const int* in_sizes, int n_in,
                              void* d_out, int out_size, void* d_ws, size_t ws_size,
                              hipStream_t stream) {
    const float* input  = (const float*)d_in[0];
    const float* hidden = (const float*)d_in[1];
    const float* Wih    = (const float*)d_in[2];
    const float* Whh    = (const float*)d_in[3];
    const float* bih    = (const float*)d_in[4];
    const float* bhh    = (const float*)d_in[5];
    float* out = (float*)d_out;

    // ws layout: gi_r (M*H f32) | sentinel ring (16 pairs x 4 x 1536 u32)
    float*    giR  = (float*)d_ws;
    unsigned* ring = (unsigned*)(giR + (size_t)Md * Hd);

    k_init<<<(NPAIR * RINGD * RVALS) / 256, 256, 0, stream>>>(hidden, ring);
    k_gemm<<<512 * 12, 256, 0, stream>>>(input, Wih, bih, giR, out);
    k_scan<<<NPAIR * SPW, THRS, 0, stream>>>(Whh, bhh, giR, out, ring);
}

// Round 7
// 4258.149 us; speedup vs baseline: 2.0193x; 1.4088x over previous
//
#include <hip/hip_runtime.h>
#include <hip/hip_bf16.h>

#define Hd 768
#define Bd 32
#define Td 1024
#define Md (Bd*Td)

// scan: 16 independent groups (1 batch-pair each) x 16 WGs (48 g-rows each)
#define NPAIR 16
#define SPW   16        // slices (WGs) per group
#define GPW   48        // g-rows per WG
#define THRS  384       // threads per scan WG (6 waves)
#define RINGD 4         // ring depth (protocol-proven in R3)
#define SENT_U 0x7FC00000u   // qNaN sentinel; tanh output bits can never equal it
#define RVALS (2*Hd)    // words per ring region per group (2 batches x 768)

typedef unsigned int u32x4 __attribute__((ext_vector_type(4)));
typedef float f32x2 __attribute__((ext_vector_type(2)));

static __device__ __forceinline__ f32x2 splat2(float v) { f32x2 r; r.x = v; r.y = v; return r; }

// ---------------- init: ring region 0 = h0, regions 1..3 = sentinel ----------------
__global__ __launch_bounds__(256) void k_init(const float* __restrict__ hid,
                                              unsigned* __restrict__ ring) {
    int i = blockIdx.x * 256 + threadIdx.x;          // 16*4*1536 = 98304 total
    const int p   = i / (RINGD * RVALS);
    const int rem = i % (RINGD * RVALS);
    const int r   = rem / RVALS;
    const int q   = rem % RVALS;
    const int bb  = q / Hd;
    const int k   = q % Hd;
    unsigned v = SENT_U;
    if (r == 0) v = ((const unsigned*)hid)[(p * 2 + bb) * Hd + k];
    ring[i] = v;
}

// ---------------- phase 1: gi_r / gi_n GEMM (unchanged) ----------------
__global__ __launch_bounds__(256, 2) void k_gemm(const float* __restrict__ A,
                                                 const float* __restrict__ Wih,
                                                 const float* __restrict__ bih,
                                                 float* __restrict__ giR,
                                                 float* __restrict__ giN) {
    __shared__ float As[16][68];
    __shared__ float Brs[16][68];
    __shared__ float Bns[16][68];
    const int tid = threadIdx.x;
    const int mb = blockIdx.x & 511;
    const int nb = blockIdx.x >> 9;
    const int lm = tid >> 2;
    const int lk = (tid & 3) << 2;
    const int tx = tid & 15;
    const int ty = tid >> 4;

    const float* pA = A   + (size_t)(mb * 64 + lm) * Hd + lk;
    const float* pR = Wih + (size_t)(nb * 64 + lm) * Hd + lk;
    const float* pN = Wih + (size_t)(2 * Hd + nb * 64 + lm) * Hd + lk;

    float accR[4][4] = {{0.f}};
    float accN[4][4] = {{0.f}};

    for (int kt = 0; kt < Hd; kt += 16) {
        float4 va = *(const float4*)(pA + kt);
        float4 vr = *(const float4*)(pR + kt);
        float4 vn = *(const float4*)(pN + kt);
        __syncthreads();
        As[lk+0][lm]=va.x; As[lk+1][lm]=va.y; As[lk+2][lm]=va.z; As[lk+3][lm]=va.w;
        Brs[lk+0][lm]=vr.x; Brs[lk+1][lm]=vr.y; Brs[lk+2][lm]=vr.z; Brs[lk+3][lm]=vr.w;
        Bns[lk+0][lm]=vn.x; Bns[lk+1][lm]=vn.y; Bns[lk+2][lm]=vn.z; Bns[lk+3][lm]=vn.w;
        __syncthreads();
        #pragma unroll
        for (int k = 0; k < 16; ++k) {
            float4 a4 = *(const float4*)&As[k][ty << 2];
            float4 r4 = *(const float4*)&Brs[k][tx << 2];
            float4 n4 = *(const float4*)&Bns[k][tx << 2];
            float av[4] = {a4.x, a4.y, a4.z, a4.w};
            float rv[4] = {r4.x, r4.y, r4.z, r4.w};
            float nv[4] = {n4.x, n4.y, n4.z, n4.w};
            #pragma unroll
            for (int i = 0; i < 4; ++i)
                #pragma unroll
                for (int j = 0; j < 4; ++j) {
                    accR[i][j] += av[i] * rv[j];
                    accN[i][j] += av[i] * nv[j];
                }
        }
    }

    const int m0 = mb * 64 + (ty << 2);
    const int g0 = nb * 64 + (tx << 2);
    float4 bR = *(const float4*)(bih + g0);
    float4 bN = *(const float4*)(bih + 2 * Hd + g0);
    #pragma unroll
    for (int i = 0; i < 4; ++i) {
        float4 oR = { accR[i][0]+bR.x, accR[i][1]+bR.y, accR[i][2]+bR.z, accR[i][3]+bR.w };
        float4 oN = { accN[i][0]+bN.x, accN[i][1]+bN.y, accN[i][2]+bN.z, accN[i][3]+bN.w };
        *(float4*)(giR + (size_t)(m0 + i) * Hd + g0) = oR;
        *(float4*)(giN + (size_t)(m0 + i) * Hd + g0) = oN;
    }
}

// ---------------- phase 2: sentinel-ring scan, register-resident weights ----
// 256 WGs = 16 pairs x 16 slices; 384 threads = (gl 0..23) x (ks 0..15).
// NO occupancy bound: weights (96 f32x2/thread) stay in VGPRs (~250 regs).
// Symmetric protocol, ONE barrier/step:
//   A. gi[t+1] prefetch (lanes ks<4; drained free by poll vmcnt)
//   B. per-wave poll of own 16B slot in region t%4; stage to LDS
//   C. reset own slot in region (t+2)%4
//   D. __syncthreads
//   E. pk_fma matvec + 16-lane butterfly
//   F. lanes ks<4: gate epilogue for their (sub,bb)
//   G. vmcnt(0)  (reset store long retired -> ~free)
//   H. lanes ks<4: ring store (sc0sc1) + out store
// Reset-before-produce invariant preserved per wave by G (R3 proof).
__global__ __launch_bounds__(THRS) void k_scan(const float* __restrict__ Whh,
                                               const float* __restrict__ bhh,
                                               const float* __restrict__ giR,
                                               float* __restrict__ out,   // giN in, h out
                                               unsigned* __restrict__ ring) {
    __shared__ float hs[2 * RVALS];    // parity x (bb*768 + k)
    const int tid = threadIdx.x;
    const int gl  = tid >> 4;          // 0..23
    const int ks  = tid & 15;          // 0..15
    const int p   = blockIdx.x >> 4;   // pair 0..15
    const int s   = blockIdx.x & 15;   // slice 0..15
    const int b0  = p * 2;
    unsigned* ringp = ring + (size_t)p * RINGD * RVALS;

    // stationary weights: wv[sub][j*4+c] = {W_hr, W_hn}[g][k], g=48s+24sub+gl, k=4ks+64j+c
    f32x2 wv[2][48];
    #pragma unroll
    for (int sub = 0; sub < 2; ++sub) {
        const int g = s * GPW + sub * 24 + gl;
        #pragma unroll
        for (int j = 0; j < 12; ++j) {
            float4 a = *(const float4*)(Whh + (size_t)g * Hd + (ks << 2) + (j << 6));
            float4 b = *(const float4*)(Whh + (size_t)(2 * Hd + g) * Hd + (ks << 2) + (j << 6));
            wv[sub][j*4+0].x=a.x; wv[sub][j*4+0].y=b.x;
            wv[sub][j*4+1].x=a.y; wv[sub][j*4+1].y=b.y;
            wv[sub][j*4+2].x=a.z; wv[sub][j*4+2].y=b.z;
            wv[sub][j*4+3].x=a.w; wv[sub][j*4+3].y=b.w;
        }
    }

    // per-output-lane state (lanes ks<4 own (sub=ks&1, bb=ks>>1))
    const int osub = ks & 1, obb = ks >> 1;
    const int og   = s * GPW + osub * 24 + gl;          // my output row
    float obr = 0.f, obn = 0.f, gRv = 0.f, gNv = 0.f;
    if (ks < 4) {
        obr = bhh[og];
        obn = bhh[2 * Hd + og];
        const size_t mi = ((size_t)(b0 + obb) * Td) * Hd + og;
        gRv = giR[mi];
        gNv = out[mi];
    }

    for (int t = 0; t < Td; ++t) {
        // A. prefetch gi[t+1] (plain loads; poll's vmcnt drains them for free)
        float gR2 = 0.f, gN2 = 0.f;
        if (ks < 4 && t + 1 < Td) {
            const size_t mi = ((size_t)(b0 + obb) * Td + (t + 1)) * Hd + og;
            gR2 = giR[mi];
            gN2 = out[mi];
        }

        // B. per-wave poll of own dwordx4 slot; first probe sleep-free
        const unsigned* myp = ringp + (t & 3) * RVALS + (tid << 2);
        float* hsl = hs + (t & 1) * RVALS;
        u32x4 w;
        asm volatile("global_load_dwordx4 %0, %1, off sc0 sc1\n\ts_waitcnt vmcnt(0)"
                     : "=v"(w) : "v"(myp) : "memory");
        while (w.x == SENT_U || w.y == SENT_U || w.z == SENT_U || w.w == SENT_U) {
            __builtin_amdgcn_s_sleep(1);
            asm volatile("global_load_dwordx4 %0, %1, off sc0 sc1\n\ts_waitcnt vmcnt(0)"
                         : "=v"(w) : "v"(myp) : "memory");
        }
        *(u32x4*)((unsigned*)hsl + (tid << 2)) = w;

        // C. reset own slot of region (t+2)%4 (ack ordered before H by G)
        {
            const unsigned* rp = ringp + ((t + 2) & 3) * RVALS + (tid << 2);
            u32x4 sv = { SENT_U, SENT_U, SENT_U, SENT_U };
            asm volatile("global_store_dwordx4 %0, %1, off sc0 sc1"
                         :: "v"(rp), "v"(sv) : "memory");
        }

        // D. staging complete
        __syncthreads();

        // E. matvec: 2 sub x 2 bb x 48 k, packed {R,N} -> 192 v_pk_fma_f32
        f32x2 a2[2][2];
        a2[0][0] = splat2(0.f); a2[0][1] = splat2(0.f);
        a2[1][0] = splat2(0.f); a2[1][1] = splat2(0.f);
        #pragma unroll
        for (int bb = 0; bb < 2; ++bb) {
            #pragma unroll
            for (int j = 0; j < 12; ++j) {
                float4 h4 = *(const float4*)&hsl[bb * Hd + (ks << 2) + (j << 6)];
                #pragma unroll
                for (int sub = 0; sub < 2; ++sub) {
                    a2[sub][bb] = __builtin_elementwise_fma(splat2(h4.x), wv[sub][j*4+0], a2[sub][bb]);
                    a2[sub][bb] = __builtin_elementwise_fma(splat2(h4.y), wv[sub][j*4+1], a2[sub][bb]);
                    a2[sub][bb] = __builtin_elementwise_fma(splat2(h4.z), wv[sub][j*4+2], a2[sub][bb]);
                    a2[sub][bb] = __builtin_elementwise_fma(splat2(h4.w), wv[sub][j*4+3], a2[sub][bb]);
                }
            }
        }
        // butterfly over the 16 ks lanes (per component)
        #pragma unroll
        for (int sub = 0; sub < 2; ++sub)
            #pragma unroll
            for (int bb = 0; bb < 2; ++bb)
                #pragma unroll
                for (int off = 8; off >= 1; off >>= 1) {
                    a2[sub][bb].x += __shfl_xor(a2[sub][bb].x, off);
                    a2[sub][bb].y += __shfl_xor(a2[sub][bb].y, off);
                }

        // F. epilogue on lanes ks<4 (each owns one (sub,bb); static select)
        float hnew = 0.f;
        if (ks < 4) {
            f32x2 mine = osub ? (obb ? a2[1][1] : a2[1][0])
                              : (obb ? a2[0][1] : a2[0][0]);
            const float r = 1.f / (1.f + __expf(-(gRv + mine.x + obr)));
            hnew = tanhf(gNv + r * (mine.y + obn));
            gRv = gR2; gNv = gN2;
        }

        // G. order reset ack before produce (reset retired during E -> ~free)
        asm volatile("s_waitcnt vmcnt(0)" ::: "memory");

        // H. produce h_{t+1} word + out[:,t]
        if (ks < 4) {
            const unsigned* dp = ringp + ((t + 1) & 3) * RVALS + obb * Hd + og;
            const unsigned hbits = __float_as_uint(hnew);
            asm volatile("global_store_dword %0, %1, off sc0 sc1"
                         :: "v"(dp), "v"(hbits) : "memory");
            out[((size_t)(b0 + obb) * Td + t) * Hd + og] = hnew;
        }
    }
}

extern "C" void kernel_launch(void* const* d_in, const int* in_sizes, int n_in,
                              void* d_out, int out_size, void* d_ws, size_t ws_size,
                              hipStream_t stream) {
    const float* input  = (const float*)d_in[0];
    const float* hidden = (const float*)d_in[1];
    const float* Wih    = (const float*)d_in[2];
    const float* Whh    = (const float*)d_in[3];
    const float* bih    = (const float*)d_in[4];
    const float* bhh    = (const float*)d_in[5];
    float* out = (float*)d_out;

    // ws layout: gi_r (M*H f32) | sentinel ring (16 pairs x 4 x 1536 u32)
    float*    giR  = (float*)d_ws;
    unsigned* ring = (unsigned*)(giR + (size_t)Md * Hd);

    k_init<<<(NPAIR * RINGD * RVALS) / 256, 256, 0, stream>>>(hidden, ring);
    k_gemm<<<512 * 12, 256, 0, stream>>>(input, Wih, bih, giR, out);
    k_scan<<<NPAIR * SPW, THRS, 0, stream>>>(Whh, bhh, giR, out, ring);
}